// Round 3
// baseline (511.151 us; speedup 1.0000x reference)
//
#include <hip/hip_runtime.h>
#include <stdint.h>

// ---------------- problem constants ----------------
constexpr int Bn = 64;
constexpr int Nn = 8;
constexpr int Vn = 128000;
constexpr int CH = 32;            // chunks per row (blocks per batch row)
constexpr int CHUNK = Vn / CH;    // 4000 floats
constexpr int F4 = CHUNK / 4;     // 1000 float4 per chunk
constexpr float EPSf = 1e-20f;
constexpr float TINYf = 1.17549435082228751e-38f;  // FLT_MIN, np.finfo(f32).tiny

// ---------------- Threefry-2x32 (JAX-exact) ----------------
struct TFOut { uint32_t a, b; };

__host__ __device__ constexpr TFOut tf2x32(uint32_t k0, uint32_t k1,
                                           uint32_t x0, uint32_t x1) {
  uint32_t k2 = k0 ^ k1 ^ 0x1BD11BDAu;
  x0 += k0; x1 += k1;
#define TFR(r) { x0 += x1; x1 = (uint32_t)((x1 << (r)) | (x1 >> (32 - (r)))); x1 ^= x0; }
  TFR(13) TFR(15) TFR(26) TFR(6)
  x0 += k1; x1 += k2 + 1u;
  TFR(17) TFR(29) TFR(16) TFR(24)
  x0 += k2; x1 += k0 + 2u;
  TFR(13) TFR(15) TFR(26) TFR(6)
  x0 += k0; x1 += k1 + 3u;
  TFR(17) TFR(29) TFR(16) TFR(24)
  x0 += k1; x1 += k2 + 4u;
  TFR(13) TFR(15) TFR(26) TFR(6)
  x0 += k2; x1 += k0 + 5u;
#undef TFR
  return TFOut{x0, x1};
}

// jax.random.key(1) -> (0,1); threefry_partitionable=True split(key,3):
// key_i = full threefry output at counter (hi,lo)=(0,i).  [verified R2: passed, absmax=0]
constexpr TFOut KU  = tf2x32(0u, 1u, 0u, 0u);  // ku
constexpr TFOut KR  = tf2x32(0u, 1u, 0u, 1u);  // kr
constexpr TFOut KB_ = tf2x32(0u, 1u, 0u, 2u);  // kb

// ---------------- device helpers ----------------
__device__ __forceinline__ float jax_u01(uint32_t bits) {
  return __uint_as_float((bits >> 9) | 0x3f800000u) - 1.0f;  // [0,1)
}

// partitionable random_bits(32): counter (0, t); bits = out0 ^ out1
__device__ __forceinline__ uint32_t rbits(uint32_t k0, uint32_t k1, uint32_t t) {
  TFOut o = tf2x32(k0, k1, 0u, t);
  return o.a ^ o.b;
}

// -log(u) term of the gumbel; always > 0 (u + tiny clamped to [tiny, 1))
__device__ __forceinline__ float neglog_u(uint32_t k0, uint32_t k1, uint32_t t) {
  float u = jax_u01(rbits(k0, k1, t));
  float uu = fmaxf(TINYf, u + TINYf);
  return -logf(uu);
}

// order-preserving float->uint, packed with ~v so 64-bit max == first-index argmax
__device__ __forceinline__ unsigned long long packsc(float s, uint32_t v) {
  uint32_t u = __float_as_uint(s);
  uint32_t m = (u & 0x80000000u) ? ~u : (u | 0x80000000u);
  return ((unsigned long long)m << 32) | (unsigned long long)(~v);
}

// accept bit for flat draft position j (bit-exact vs reference)
__device__ __forceinline__ int accept_bit(int j, const int* __restrict__ ids,
                                          const float* __restrict__ draft,
                                          const float* __restrict__ verify) {
  int b = j >> 3, n = j & 7;
  float u = jax_u01(rbits(KU.a, KU.b, (uint32_t)j));
  int tok = ids[j];
  float p = verify[(size_t)(b * (Nn + 1) + n) * Vn + tok];
  float q = draft[(size_t)(b * Nn + n) * Vn + tok];
  return (u * q < p) ? 1 : 0;
}

// ---------------- init: zero R and cnt (d_ws is poisoned 0xAA each call) ----------------
__global__ void __launch_bounds__(128)
KInit(unsigned long long* __restrict__ R, unsigned int* __restrict__ cnt) {
  int i = threadIdx.x;
  if (i < Bn) R[i] = 0ull;        // 0 < packsc(any non-NaN score, v)
  else if (i < 2 * Bn) cnt[i - Bn] = 0u;
}

// ---------------- fused kernel: accept/emitted + outputs + gumbel-argmax + finalize ----------------
// score = gumbel + log(x) reformulated as log(x / (-log u)): argmax-equivalent, 1 logf saved.
// Normalization by Sm dropped: argmax[g + log(r/Sm + EPS)] == argmax[g + log(r + Sm*EPS)]
// (per-row constant shift); EPS-vs-Sm*EPS only perturbs r <~ 1e-17 which cannot win.
__global__ void __launch_bounds__(256)
K1(const int* __restrict__ ids, const float* __restrict__ draft,
   const float* __restrict__ verify, int* __restrict__ out,
   unsigned long long* __restrict__ R, unsigned int* __restrict__ cnt) {
  int blk = blockIdx.x;
  int b = blk >> 5, c = blk & 31;
  __shared__ int s_acc[8];
  __shared__ unsigned long long smax[256];
  if (threadIdx.x < 8) s_acc[threadIdx.x] = accept_bit(b * 8 + threadIdx.x, ids, draft, verify);
  __syncthreads();
  int em = 0;
  while (em < 8 && s_acc[em]) em++;

  if (c == 0 && threadIdx.x == 0) {
    int acc = s_acc[0] + s_acc[1] + s_acc[2] + s_acc[3] + s_acc[4] + s_acc[5] + s_acc[6] + s_acc[7];
    out[Bn * (Nn + 1) + b] = acc;        // accepted_token_num
    out[Bn * (Nn + 1) + Bn + b] = em;    // emitted_token_num
    // slot em is written ONLY by the last-finishing block (no race)
    for (int pos = 0; pos < em; pos++) out[b * (Nn + 1) + pos] = ids[b * Nn + pos];
    for (int pos = em + 1; pos <= Nn; pos++) out[b * (Nn + 1) + pos] = -1;
  }

  float best = -__builtin_inff();
  uint32_t bestv = 0u;

  if (em < Nn) {
    // recovered token: argmax_v [ log((max(t-d,0)+EPS) / (-log u_v)) ]
    const float4* t4 = (const float4*)(verify + (size_t)(b * (Nn + 1) + em) * Vn + c * CHUNK);
    const float4* d4 = (const float4*)(draft + (size_t)(b * Nn + em) * Vn + c * CHUNK);
    uint32_t trow = (uint32_t)(b * Nn + em) * (uint32_t)Vn;
    for (int i = threadIdx.x; i < F4; i += 256) {
      float4 t = t4[i], d = d4[i];
      uint32_t v0 = (uint32_t)(c * CHUNK + i * 4);
      float tv[4] = {t.x, t.y, t.z, t.w};
      float dv[4] = {d.x, d.y, d.z, d.w};
#pragma unroll
      for (int k = 0; k < 4; k++) {
        float x = fmaxf(tv[k] - dv[k], 0.0f) + EPSf;
        float nl = neglog_u(KR.a, KR.b, trow + v0 + k);
        float sc = logf(x / nl);
        if (sc > best) { best = sc; bestv = v0 + k; }  // ascending v => first occurrence
      }
    }
  } else {
    // bonus token: argmax_v [ log((verify[b,N,v]+EPS) / (-log u_v)) ]
    const float4* p4 = (const float4*)(verify + (size_t)(b * (Nn + 1) + Nn) * Vn + c * CHUNK);
    uint32_t trow = (uint32_t)b * (uint32_t)Vn;
    for (int i = threadIdx.x; i < F4; i += 256) {
      float4 p = p4[i];
      uint32_t v0 = (uint32_t)(c * CHUNK + i * 4);
      float pv[4] = {p.x, p.y, p.z, p.w};
#pragma unroll
      for (int k = 0; k < 4; k++) {
        float x = pv[k] + EPSf;
        float nl = neglog_u(KB_.a, KB_.b, trow + v0 + k);
        float sc = logf(x / nl);
        if (sc > best) { best = sc; bestv = v0 + k; }
      }
    }
  }

  smax[threadIdx.x] = packsc(best, bestv);
  __syncthreads();
  for (int st = 128; st > 0; st >>= 1) {
    if (threadIdx.x < st) {
      unsigned long long o = smax[threadIdx.x + st];
      if (o > smax[threadIdx.x]) smax[threadIdx.x] = o;
    }
    __syncthreads();
  }

  if (threadIdx.x == 0) {
    atomicMax(&R[b], smax[0]);            // device-scope
    __threadfence();
    if (atomicAdd(&cnt[b], 1u) == (unsigned)(CH - 1)) {
      // all 32 blocks of row b have published; atomic read of final max
      unsigned long long v = atomicMax(&R[b], 0ull);
      out[b * (Nn + 1) + em] = (int)(~(uint32_t)(v & 0xFFFFFFFFull));
    }
  }
}

// ---------------- launch ----------------
extern "C" void kernel_launch(void* const* d_in, const int* in_sizes, int n_in,
                              void* d_out, int out_size, void* d_ws, size_t ws_size,
                              hipStream_t stream) {
  const int* ids = (const int*)d_in[0];
  const float* draft = (const float*)d_in[1];
  const float* verify = (const float*)d_in[2];
  int* out = (int*)d_out;

  char* w = (char*)d_ws;
  unsigned long long* R = (unsigned long long*)w;          // 64 * 8 B
  unsigned int* cnt = (unsigned int*)(w + Bn * 8);         // 64 * 4 B

  KInit<<<dim3(1), dim3(128), 0, stream>>>(R, cnt);
  K1<<<dim3(Bn * CH), dim3(256), 0, stream>>>(ids, draft, verify, out, R, cnt);
}